// Round 9
// baseline (62.164 us; speedup 1.0000x reference)
//
#include <hip/hip_runtime.h>
#include <hip/hip_bf16.h>

// B=2, N=512, C=256
// score[b,i,j] = sum_c relu(q_ic+k_jc) = 0.5*(Qs_i + Ks_j + sum_c|q_ic+k_jc|); Qs_i cancels.
// out = softmax(score) @ v @ Wp^T + bp = P @ (x @ (Wp@Wv)^T) + bp   [associativity]
// Pipeline: K0 Wvp=Wp@Wv -> K1 q,k,Vp(+Ksp) -> K2 P(raw exp)+ml -> K3 (scaled P)@Vp + bias.

#define QSTR 132   // q/k LDS stride (dwords)

// ---------------- Kernel 0: Wvp = Wp @ Wv  (256x256x256) ----------------
__global__ __launch_bounds__(256) void wvp_gemm(
    const float* __restrict__ Wp, const float* __restrict__ Wv, float* __restrict__ Wvp)
{
    const int row0 = blockIdx.x * 32;   // d rows of Wvp (= rows of Wp)
    const int e0   = blockIdx.y * 64;

    __shared__ __attribute__((aligned(16))) float AT[32][36];  // [c][d]
    __shared__ __attribute__((aligned(16))) float BT[32][68];  // [c][e]

    const int t = threadIdx.x;
    const int ty = t >> 4, tx = t & 15;
    float acc[2][4] = {};

    for (int c0 = 0; c0 < 256; c0 += 32) {
        {   // A: Wp[d][c] transposed
            int r = t >> 3, cb = (t & 7) * 4;
            float4 a = *(const float4*)&Wp[(size_t)(row0 + r) * 256 + c0 + cb];
            AT[cb+0][r]=a.x; AT[cb+1][r]=a.y; AT[cb+2][r]=a.z; AT[cb+3][r]=a.w;
        }
        {   // B: Wv[c][e] direct
            int cc = t >> 3, ec = (t & 7) * 8;
            *(float4*)&BT[cc][ec]     = *(const float4*)&Wv[(size_t)(c0 + cc) * 256 + e0 + ec];
            *(float4*)&BT[cc][ec + 4] = *(const float4*)&Wv[(size_t)(c0 + cc) * 256 + e0 + ec + 4];
        }
        __syncthreads();
#pragma unroll
        for (int c = 0; c < 32; ++c) {
            float2 a  = *(const float2*)&AT[c][ty * 2];
            float4 w4 = *(const float4*)&BT[c][tx * 4];
            acc[0][0]+=a.x*w4.x; acc[0][1]+=a.x*w4.y; acc[0][2]+=a.x*w4.z; acc[0][3]+=a.x*w4.w;
            acc[1][0]+=a.y*w4.x; acc[1][1]+=a.y*w4.y; acc[1][2]+=a.y*w4.z; acc[1][3]+=a.y*w4.w;
        }
        __syncthreads();
    }
#pragma unroll
    for (int rr = 0; rr < 2; ++rr)
        *(float4*)&Wvp[(size_t)(row0 + ty * 2 + rr) * 256 + e0 + tx * 4] =
            make_float4(acc[rr][0], acc[rr][1], acc[rr][2], acc[rr][3]);
}

// ---------------- Kernel 1: q (transposed) + Ksp, k, Vp = x@Wvp^T ----------------
__global__ __launch_bounds__(256, 2) void gemm_qkv(
    const float* __restrict__ x,
    const float* __restrict__ Wq, const float* __restrict__ Wk, const float* __restrict__ Wvp,
    float4* __restrict__ qt4, float* __restrict__ k, float* __restrict__ Vp,
    float* __restrict__ Ksp)
{
    const int z = blockIdx.z;
    const float* W = (z == 0) ? Wq : ((z == 1) ? Wk : Wvp);
    const int row0 = blockIdx.x * 32;
    const int d0   = blockIdx.y * 64;

    __shared__ __attribute__((aligned(16))) float AT[2][32][36];
    __shared__ __attribute__((aligned(16))) float WT[2][32][68];

    const int tid = threadIdx.x;
    const int ty = tid >> 4, tx = tid & 15;
    const int ar = tid >> 3, ac = (tid & 7) * 4;
    const int wd = tid >> 2, wc = (tid & 3) * 8;

    const float* xg = x + (size_t)(row0 + ar) * 256 + ac;
    const float* wg = W + (size_t)(d0 + wd) * 256 + wc;

    float4 ra  = *(const float4*)xg;
    float4 rw0 = *(const float4*)wg;
    float4 rw1 = *(const float4*)(wg + 4);

    AT[0][ac+0][ar]=ra.x;  AT[0][ac+1][ar]=ra.y;  AT[0][ac+2][ar]=ra.z;  AT[0][ac+3][ar]=ra.w;
    WT[0][wc+0][wd]=rw0.x; WT[0][wc+1][wd]=rw0.y; WT[0][wc+2][wd]=rw0.z; WT[0][wc+3][wd]=rw0.w;
    WT[0][wc+4][wd]=rw1.x; WT[0][wc+5][wd]=rw1.y; WT[0][wc+6][wd]=rw1.z; WT[0][wc+7][wd]=rw1.w;
    __syncthreads();

    float acc[2][4] = {};

#pragma unroll 1
    for (int kc = 0; kc < 8; ++kc) {
        const int cur = kc & 1;
        if (kc < 7) {
            ra  = *(const float4*)(xg + (kc + 1) * 32);
            rw0 = *(const float4*)(wg + (kc + 1) * 32);
            rw1 = *(const float4*)(wg + (kc + 1) * 32 + 4);
        }
#pragma unroll
        for (int c = 0; c < 32; ++c) {
            float2 a  = *(const float2*)&AT[cur][c][ty * 2];
            float4 w4 = *(const float4*)&WT[cur][c][tx * 4];
            acc[0][0]+=a.x*w4.x; acc[0][1]+=a.x*w4.y; acc[0][2]+=a.x*w4.z; acc[0][3]+=a.x*w4.w;
            acc[1][0]+=a.y*w4.x; acc[1][1]+=a.y*w4.y; acc[1][2]+=a.y*w4.z; acc[1][3]+=a.y*w4.w;
        }
        if (kc < 7) {
            const int nx = cur ^ 1;
            AT[nx][ac+0][ar]=ra.x;  AT[nx][ac+1][ar]=ra.y;  AT[nx][ac+2][ar]=ra.z;  AT[nx][ac+3][ar]=ra.w;
            WT[nx][wc+0][wd]=rw0.x; WT[nx][wc+1][wd]=rw0.y; WT[nx][wc+2][wd]=rw0.z; WT[nx][wc+3][wd]=rw0.w;
            WT[nx][wc+4][wd]=rw1.x; WT[nx][wc+5][wd]=rw1.y; WT[nx][wc+6][wd]=rw1.z; WT[nx][wc+7][wd]=rw1.w;
            __syncthreads();
        }
    }

    if (z == 0) {
#pragma unroll
        for (int rr = 0; rr < 2; ++rr)
            qt4[(size_t)(d0 / 4 + tx) * 1024 + row0 + ty * 2 + rr] =
                make_float4(acc[rr][0], acc[rr][1], acc[rr][2], acc[rr][3]);
    } else {
        float* out = (z == 1) ? k : Vp;
#pragma unroll
        for (int rr = 0; rr < 2; ++rr)
            *(float4*)&out[(size_t)(row0 + ty * 2 + rr) * 256 + d0 + tx * 4] =
                make_float4(acc[rr][0], acc[rr][1], acc[rr][2], acc[rr][3]);
        if (z == 1) {
#pragma unroll
            for (int rr = 0; rr < 2; ++rr) {
                float kp = acc[rr][0] + acc[rr][1] + acc[rr][2] + acc[rr][3];
#pragma unroll
                for (int d = 1; d < 16; d <<= 1) kp += __shfl_xor(kp, d, 16);
                if (tx == 0)
                    Ksp[(size_t)(d0 >> 6) * 1024 + row0 + ty * 2 + rr] = kp;
            }
        }
    }
}

// ---------------- Kernel 2: score + per-js softmax -> PT (raw exp) + ml ----------------
// 512 thr = 8 waves, lane = query row (64), wave w = j-quad. No v, no PV, no pacc.
__global__ __launch_bounds__(512) void attn_score(
    const float4* __restrict__ qt4, const float* __restrict__ kk,
    const float* __restrict__ Ksp, float* __restrict__ PT, float* __restrict__ ml)
{
    const int it = blockIdx.x;          // 0..15
    const int js = blockIdx.y;          // 0..15
    const int b  = it >> 3;
    const int irow0 = it * 64;
    const int jrow0 = b * 512 + js * 32;

    __shared__ __attribute__((aligned(16))) float qbuf[64 * QSTR];
    __shared__ __attribute__((aligned(16))) float kbuf[32 * QSTR];
    __shared__ float smax[8][65];
    __shared__ float psum[8][65];

    const int t = threadIdx.x;
    const int w = t >> 6;
    const int l = t & 63;
    const int j0 = w * 4;

    float s[4] = {0.f, 0.f, 0.f, 0.f};

    for (int h = 0; h < 2; ++h) {
#pragma unroll
        for (int u = 0; u < 4; ++u) {
            int idx = u * 512 + t;
            int c4 = idx >> 6, row = idx & 63;
            *(float4*)&qbuf[row * QSTR + c4 * 4] =
                qt4[(size_t)(h * 32 + c4) * 1024 + irow0 + row];
        }
#pragma unroll
        for (int u = 0; u < 2; ++u) {
            int idx = u * 512 + t;
            int row = idx >> 5, c4 = idx & 31;
            *(float4*)&kbuf[row * QSTR + c4 * 4] =
                *(const float4*)&kk[(size_t)(jrow0 + row) * 256 + h * 128 + c4 * 4];
        }
        __syncthreads();

        const float* qrow = &qbuf[l * QSTR];
        const float* k0p = &kbuf[(j0 + 0) * QSTR];
        const float* k1p = &kbuf[(j0 + 1) * QSTR];
        const float* k2p = &kbuf[(j0 + 2) * QSTR];
        const float* k3p = &kbuf[(j0 + 3) * QSTR];

        float4 Aqa,Aqb,Ak0a,Ak0b,Ak1a,Ak1b,Ak2a,Ak2b,Ak3a,Ak3b;
        float4 Bqa,Bqb,Bk0a,Bk0b,Bk1a,Bk1b,Bk2a,Bk2b,Bk3a,Bk3b;

#define LDCH(P, c) \
        P##qa  = *(const float4*)(qrow + (c)); P##qb  = *(const float4*)(qrow + (c) + 4); \
        P##k0a = *(const float4*)(k0p + (c)); P##k0b = *(const float4*)(k0p + (c) + 4); \
        P##k1a = *(const float4*)(k1p + (c)); P##k1b = *(const float4*)(k1p + (c) + 4); \
        P##k2a = *(const float4*)(k2p + (c)); P##k2b = *(const float4*)(k2p + (c) + 4); \
        P##k3a = *(const float4*)(k3p + (c)); P##k3b = *(const float4*)(k3p + (c) + 4);
#define CMPJ(jj, QA, QB, KA, KB) \
        s[jj] += fabsf(QA.x + KA.x); s[jj] += fabsf(QA.y + KA.y); \
        s[jj] += fabsf(QA.z + KA.z); s[jj] += fabsf(QA.w + KA.w); \
        s[jj] += fabsf(QB.x + KB.x); s[jj] += fabsf(QB.y + KB.y); \
        s[jj] += fabsf(QB.z + KB.z); s[jj] += fabsf(QB.w + KB.w);
#define CMPALL(P) \
        CMPJ(0, P##qa, P##qb, P##k0a, P##k0b) CMPJ(1, P##qa, P##qb, P##k1a, P##k1b) \
        CMPJ(2, P##qa, P##qb, P##k2a, P##k2b) CMPJ(3, P##qa, P##qb, P##k3a, P##k3b)

        LDCH(A, 0)
#pragma unroll 1
        for (int c0 = 0; c0 < 128; c0 += 16) {
            LDCH(B, c0 + 8)
            CMPALL(A)
            int cn = (c0 + 16) & 127;
            LDCH(A, cn)
            CMPALL(B)
        }
        __syncthreads();
    }

    // score' = 0.5*(Sabs + Ks_j)
    const int jbase = jrow0 + j0;
    float sc[4];
#pragma unroll
    for (int jj = 0; jj < 4; ++jj) {
        float ks = Ksp[jbase + jj] + Ksp[1024 + jbase + jj]
                 + Ksp[2048 + jbase + jj] + Ksp[3072 + jbase + jj];
        sc[jj] = 0.5f * (s[jj] + ks);
    }
    smax[w][l] = fmaxf(fmaxf(sc[0], sc[1]), fmaxf(sc[2], sc[3]));
    __syncthreads();

    float m = smax[0][l];
#pragma unroll
    for (int ww = 1; ww < 8; ++ww) m = fmaxf(m, smax[ww][l]);

    float ps = 0.f;
#pragma unroll
    for (int jj = 0; jj < 4; ++jj) {
        float p = __expf(sc[jj] - m);
        ps += p;
        PT[(size_t)(js * 32 + j0 + jj) * 1024 + irow0 + l] = p;   // coalesced over l
    }
    psum[w][l] = ps;
    __syncthreads();

    if (w == 0) {
        float lsum = 0.f;
#pragma unroll
        for (int ww = 0; ww < 8; ++ww) lsum += psum[ww][l];
        *(float2*)&ml[((size_t)(irow0 + l) * 16 + js) * 2] = make_float2(m, lsum);
    }
}

// ---------------- Kernel 3: out = (scaled P) @ Vp + bias ----------------
// Tile 16 rows x 64 d, K=512 (j within batch), grid (64,4)=256 blocks.
// Combine folded into A-staging: scale by wgt[row][js], js uniform per K-chunk.
__global__ __launch_bounds__(256) void pv_proj(
    const float* __restrict__ PT, const float* __restrict__ ml,
    const float* __restrict__ Vp, const float* __restrict__ bias,
    float* __restrict__ out)
{
    const int row0 = blockIdx.x * 16;    // global row
    const int d0   = blockIdx.y * 64;
    const int b    = row0 >> 9;

    __shared__ float wgtL[16][17];
    __shared__ __attribute__((aligned(16))) float AT[2][32][18];  // [buf][j][row]
    __shared__ __attribute__((aligned(16))) float BT[2][32][68];  // [buf][j][d]

    const int t = threadIdx.x;
    const int ty = t >> 4, tx = t & 15;

    {   // wgt[row][s] = exp(m_s - M)/L   (16 rows x 16 js, one thread each)
        int r = t >> 4, s = t & 15;
        float2 e = *(const float2*)&ml[((size_t)(row0 + r) * 16 + s) * 2];
        float M = e.x;
#pragma unroll
        for (int d = 1; d < 16; d <<= 1) M = fmaxf(M, __shfl_xor(M, d, 16));
        float ex = __expf(e.x - M);
        float Lp = ex * e.y;
#pragma unroll
        for (int d = 1; d < 16; d <<= 1) Lp += __shfl_xor(Lp, d, 16);
        wgtL[r][s] = ex / Lp;
    }
    __syncthreads();

    const int cc = t >> 3;               // 0..31 (j within chunk)
    const int r2 = (t & 7) * 2;          // 2 rows
    const int ec = (t & 7) * 8;          // 8 d's
    const float* ptg = PT + (size_t)cc * 1024 + row0 + r2;
    const float* vpg = Vp + (size_t)(b * 512 + cc) * 256 + d0 + ec;

    float2 ra  = *(const float2*)ptg;
    float4 rb0 = *(const float4*)vpg;
    float4 rb1 = *(const float4*)(vpg + 4);
    {
        AT[0][cc][r2]     = ra.x * wgtL[r2][0];
        AT[0][cc][r2 + 1] = ra.y * wgtL[r2 + 1][0];
        *(float4*)&BT[0][cc][ec]     = rb0;
        *(float4*)&BT[0][cc][ec + 4] = rb1;
    }
    __syncthreads();

    float acc[4] = {0.f, 0.f, 0.f, 0.f};

#pragma unroll 1
    for (int kc = 0; kc < 16; ++kc) {
        const int cur = kc & 1;
        if (kc < 15) {
            ra  = *(const float2*)(ptg + (size_t)(kc + 1) * 32 * 1024);
            rb0 = *(const float4*)(vpg + (size_t)(kc + 1) * 32 * 256);
            rb1 = *(const float4*)(vpg + (size_t)(kc + 1) * 32 * 256 + 4);
        }
#pragma unroll
        for (int c = 0; c < 32; ++c) {
            float a   = AT[cur][c][ty];
            float4 w4 = *(const float4*)&BT[cur][c][tx * 4];
            acc[0] += a * w4.x; acc[1] += a * w4.y;
            acc[2] += a * w4.z; acc[3] += a * w4.w;
        }
        if (kc < 15) {
            const int nx = cur ^ 1;
            AT[nx][cc][r2]     = ra.x * wgtL[r2][kc + 1];
            AT[nx][cc][r2 + 1] = ra.y * wgtL[r2 + 1][kc + 1];
            *(float4*)&BT[nx][cc][ec]     = rb0;
            *(float4*)&BT[nx][cc][ec + 4] = rb1;
            __syncthreads();
        }
    }

    float4 bb = *(const float4*)&bias[d0 + tx * 4];
    *(float4*)&out[(size_t)(row0 + ty) * 256 + d0 + tx * 4] =
        make_float4(acc[0] + bb.x, acc[1] + bb.y, acc[2] + bb.z, acc[3] + bb.w);
}

extern "C" void kernel_launch(void* const* d_in, const int* in_sizes, int n_in,
                              void* d_out, int out_size, void* d_ws, size_t ws_size,
                              hipStream_t stream) {
    const float* x  = (const float*)d_in[0];
    const float* Wq = (const float*)d_in[1];
    const float* Wk = (const float*)d_in[2];
    const float* Wv = (const float*)d_in[3];
    const float* Wp = (const float*)d_in[4];
    const float* bp = (const float*)d_in[5];
    float* out = (float*)d_out;
    (void)ws_size; (void)in_sizes; (void)n_in; (void)out_size;

    float* ws = (float*)d_ws;
    const size_t BNC = (size_t)2 * 512 * 256;          // 262144
    float4* qt4 = (float4*)ws;                         // [64 c4][1024]   1 MB
    float* k    = ws + BNC;                            //                 1 MB
    float* Vp   = k + BNC;                             // [1024][256]     1 MB
    float* Ksp  = Vp + BNC;                            // [4][1024]
    float* PT   = Ksp + 4 * 1024;                      // [512 j][1024]   2 MB
    float* mlb  = PT + (size_t)512 * 1024;             // [1024][16][2]
    float* Wvp  = mlb + (size_t)1024 * 16 * 2;         // [256][256]      256 KB

    wvp_gemm<<<dim3(8, 4), 256, 0, stream>>>(Wp, Wv, Wvp);
    gemm_qkv<<<dim3(32, 4, 3), 256, 0, stream>>>(x, Wq, Wk, Wvp, qt4, k, Vp, Ksp);
    attn_score<<<dim3(16, 16), 512, 0, stream>>>(qt4, k, Ksp, PT, mlb);
    pv_proj<<<dim3(64, 4), 256, 0, stream>>>(PT, mlb, Vp, bp, out);
}